// Round 12
// baseline (357.841 us; speedup 1.0000x reference)
//
#include <hip/hip_runtime.h>
#include <stdint.h>

typedef unsigned short u16;
typedef __attribute__((ext_vector_type(8))) short short8;
typedef __attribute__((ext_vector_type(4))) short short4_t;
typedef __attribute__((ext_vector_type(4))) float f32x4;

__device__ __forceinline__ float b2f(u16 u){ union{unsigned i; float f;}v; v.i=((unsigned)u)<<16; return v.f; }
__device__ __forceinline__ u16 f2b(float f){ unsigned x=__float_as_uint(f); return (u16)((x + 0x7fffu + ((x>>16)&1u))>>16); }

#if __has_builtin(__builtin_amdgcn_exp2f)
#define EXP2F(x) __builtin_amdgcn_exp2f(x)
#else
#define EXP2F(x) exp2f(x)
#endif

#if __has_builtin(__builtin_amdgcn_mfma_f32_16x16x16_bf16)
#define MFMA16(a,b,c) __builtin_amdgcn_mfma_f32_16x16x16_bf16(a,b,c,0,0,0)
#elif __has_builtin(__builtin_amdgcn_mfma_f32_16x16x16bf16_1k)
#define MFMA16(a,b,c) __builtin_amdgcn_mfma_f32_16x16x16bf16_1k(a,b,c,0,0,0)
#else
static __device__ __forceinline__ f32x4 mfma16_asm(short4_t a, short4_t b, f32x4 c){
  __asm__("v_mfma_f32_16x16x16_bf16 %0, %1, %2, %3" : "=v"(c) : "v"(a), "v"(b), "0"(c));
  return c;
}
#define MFMA16(a,b,c) mfma16_asm(a,b,c)
#endif

__device__ __forceinline__ void async16(const void* g, void* l){
  __builtin_amdgcn_global_load_lds((const __attribute__((address_space(1))) void*)g,
                                   (__attribute__((address_space(3))) void*)l, 16, 0, 0);
}

// pack 4 fp32 (in [0,1]) -> 4 bf16 (round-half-up) as K=16 A-fragment regs
__device__ __forceinline__ short4_t pack4(f32x4 s){
  unsigned u0 = (__float_as_uint(s[0]) + 0x8000u) >> 16;
  unsigned u1 = (__float_as_uint(s[1]) + 0x8000u) & 0xffff0000u;
  unsigned u2 = (__float_as_uint(s[2]) + 0x8000u) >> 16;
  unsigned u3 = (__float_as_uint(s[3]) + 0x8000u) & 0xffff0000u;
  union { unsigned v[2]; short4_t s4; } r;
  r.v[0] = u0 | u1; r.v[1] = u2 | u3;
  return r.s4;
}

// ---------------- LayerNorm (E=1024, one block per row) ----------------
template<int IN_F32>
__global__ __launch_bounds__(256) void ln_kernel(const void* __restrict__ xin,
    const float* __restrict__ g, const float* __restrict__ b, u16* __restrict__ y)
{
  const int E = 1024;
  int row = blockIdx.x, t = threadIdx.x;
  float f0,f1,f2,f3;
  if (IN_F32){
    const float* xr = (const float*)xin + (size_t)row*E;
    float4 xv = *(const float4*)(xr + t*4);
    f0=xv.x; f1=xv.y; f2=xv.z; f3=xv.w;
  } else {
    const u16* xr = (const u16*)xin + (size_t)row*E;
    ushort4 xv = *(const ushort4*)(xr + t*4);
    f0=b2f(xv.x); f1=b2f(xv.y); f2=b2f(xv.z); f3=b2f(xv.w);
  }
  float s1 = f0+f1+f2+f3;
  float s2 = f0*f0+f1*f1+f2*f2+f3*f3;
  #pragma unroll
  for (int off=32; off>=1; off>>=1){ s1 += __shfl_xor(s1,off); s2 += __shfl_xor(s2,off); }
  __shared__ float red[8];
  int w = t>>6;
  if ((t&63)==0){ red[w]=s1; red[4+w]=s2; }
  __syncthreads();
  float S1 = red[0]+red[1]+red[2]+red[3];
  float S2 = red[4]+red[5]+red[6]+red[7];
  float mean = S1*(1.0f/E);
  float var  = S2*(1.0f/E) - mean*mean;
  float inv  = rsqrtf(var + 1e-5f);
  float4 gv = *(const float4*)(g + t*4);
  float4 bv = *(const float4*)(b + t*4);
  ushort4 o;
  o.x = f2b((f0-mean)*inv*gv.x+bv.x);
  o.y = f2b((f1-mean)*inv*gv.y+bv.y);
  o.z = f2b((f2-mean)*inv*gv.z+bv.z);
  o.w = f2b((f3-mean)*inv*gv.w+bv.w);
  *(ushort4*)(y + (size_t)row*E + t*4) = o;
}

// ---------------- fp32->bf16 64x64-tiled transpose ----------------
__global__ __launch_bounds__(256) void transpose_bt(const float* __restrict__ src, u16* __restrict__ dst,
                                                    int ld_src, int ld_dst)
{
  __shared__ u16 tile[64*66];
  int c0 = blockIdx.x*64, r0 = blockIdx.y*64;
  int t = threadIdx.x;
  #pragma unroll
  for (int i=0;i<16;++i){
    int lin = i*256 + t;
    int rr = lin>>6, cc = lin&63;
    tile[cc*66+rr] = f2b(src[(size_t)(r0+rr)*ld_src + c0+cc]);
  }
  __syncthreads();
  #pragma unroll
  for (int i=0;i<16;++i){
    int lin = i*256 + t;
    int cc = lin>>6, rr = lin&63;
    dst[(size_t)(c0+cc)*ld_dst + r0+rr] = tile[cc*66+rr];
  }
}

// ---------------- QKV weight repack ----------------
__global__ __launch_bounds__(256) void qkv_repack(const float* __restrict__ wq, const float* __restrict__ wk,
                                                  const float* __restrict__ wv, u16* __restrict__ dst)
{
  __shared__ u16 tile[64*66];
  int e0 = blockIdx.x*64;
  int sel = blockIdx.y>>4, h = blockIdx.y&15;
  const float* src = (sel==0?wq:(sel==1?wk:wv)) + (size_t)h*1024*64;
  int t = threadIdx.x;
  #pragma unroll
  for (int i=0;i<16;++i){
    int lin=i*256+t; int rr=lin>>6, cc=lin&63;
    tile[cc*66+rr] = f2b(src[(size_t)(e0+rr)*64 + cc]);
  }
  __syncthreads();
  #pragma unroll
  for (int i=0;i<16;++i){
    int lin=i*256+t; int cc=lin>>6, rr=lin&63;
    dst[(size_t)(sel*1024 + h*64 + cc)*1024 + e0+rr] = tile[cc*66+rr];
  }
}

// ---------------- V transpose: qkv V-slice -> VT[bh][64][2048] ----------------
__global__ __launch_bounds__(256) void vtrans(const u16* __restrict__ qkv, u16* __restrict__ VT)
{
  __shared__ u16 tile[64*66];
  int bh = blockIdx.y, bb = bh>>4, h = bh&15;
  int s0 = blockIdx.x*64;
  const u16* src = qkv + ((size_t)(bb*2048) + s0)*3072 + 2048 + h*64;
  int t = threadIdx.x;
  int sr = t>>3, c0 = (t&7)*8;
  #pragma unroll
  for (int half=0; half<2; ++half){
    const u16* p = src + (size_t)(sr+half*32)*3072 + c0;
    ushort4 v0 = *(const ushort4*)p;
    ushort4 v1 = *(const ushort4*)(p+4);
    uint* d = (uint*)(tile + (sr+half*32)*66 + c0);
    d[0] = (uint)v0.x | ((uint)v0.y<<16);
    d[1] = (uint)v0.z | ((uint)v0.w<<16);
    d[2] = (uint)v1.x | ((uint)v1.y<<16);
    d[3] = (uint)v1.z | ((uint)v1.w<<16);
  }
  __syncthreads();
  u16* out = VT + (size_t)bh*64*2048 + s0;
  int dw = t>>3, sc = (t&7)*8;
  #pragma unroll
  for (int half=0; half<2; ++half){
    int d = dw + half*32;
    short8 pk;
    #pragma unroll
    for (int j=0;j<8;++j) pk[j] = (short)tile[(sc+j)*66 + d];
    *(short8*)(out + (size_t)d*2048 + sc) = pk;
  }
}

// ---------------- gemm64: 64x64 tile, 4 waves, high-TLP (4 blocks/CU) ----------------
// For N=1024 shapes (FFN2, proj): 1024 blocks = 4 blocks/CU = 16 waves/CU.
// r10 measured: FFN2 64.5 -> 59.9us, occupancy 19.8 -> 37.5% (LDS-throughput-bound
// at ~86% of its read+write ceiling).
__global__ __launch_bounds__(256, 4) void gemm64(const u16* __restrict__ A, const u16* __restrict__ Bt,
    u16* __restrict__ C, float* __restrict__ Cf, int M, int N, int K,
    const float* __restrict__ bias, const u16* __restrict__ residual, int do_relu, int gx)
{
  __shared__ __align__(16) u16 As[2][64*64];
  __shared__ __align__(16) u16 Bs[2][64*64];
  int t = threadIdx.x;
  int bid = blockIdx.y * gridDim.x + blockIdx.x;
  int xcd = bid & 7, slot = bid >> 3;
  int gy = 8 / gx;
  int rx = gridDim.x / gx, ry = gridDim.y / gy;
  int col_b = (xcd % gx) * rx + (slot % rx);
  int row_b = (xcd / gx) * ry + (slot / rx);
  int row0 = row_b*64, col0 = col_b*64;
  int l = t&63, w = t>>6;
  int lr = l&15, lq = l>>4;
  (void)M;

  f32x4 acc[4];
  #pragma unroll
  for (int j=0;j<4;++j) acc[j] = f32x4{0.f,0.f,0.f,0.f};

  const u16* gA = A  + (size_t)(row0 + (t>>3))*K + (((t&7)^((t>>3)&7))<<3);
  const u16* gB = Bt + (size_t)(col0 + (t>>3))*K + (((t&7)^((t>>3)&7))<<3);
  const size_t rnd = (size_t)32*K;
  int nk = K>>6;

  #pragma unroll
  for (int r=0;r<2;++r){
    async16(gA + r*rnd, As[0] + r*2048 + t*8);
    async16(gB + r*rnd, Bs[0] + r*2048 + t*8);
  }

  int sw8 = (lr&7);
  for (int kt=0; kt<nk; ++kt){
    int cur = kt&1;
    __syncthreads();
    if (kt+1 < nk){
      int ko = (kt+1)<<6;
      #pragma unroll
      for (int r=0;r<2;++r){
        async16(gA + r*rnd + ko, As[cur^1] + r*2048 + t*8);
        async16(gB + r*rnd + ko, Bs[cur^1] + r*2048 + t*8);
      }
    }
    const u16* as = As[cur];
    const u16* bs = Bs[cur];
    #pragma unroll
    for (int kk=0;kk<2;++kk){
      int so = (((kk*4+lq)^sw8))<<3;
      short8 a = *(const short8*)(as + (w*16+lr)*64 + so);
      short8 b[4];
      #pragma unroll
      for (int j=0;j<4;++j) b[j] = *(const short8*)(bs + (j*16+lr)*64 + so);
      #pragma unroll
      for (int j=0;j<4;++j)
        acc[j] = __builtin_amdgcn_mfma_f32_16x16x32_bf16(a, b[j], acc[j], 0,0,0);
    }
  }

  #pragma unroll
  for (int j=0;j<4;++j){
    int col = col0 + j*16 + lr;
    float bv = bias ? bias[col] : 0.0f;
    #pragma unroll
    for (int r=0;r<4;++r){
      int row = row0 + w*16 + lq*4 + r;
      float v = acc[j][r] + bv;
      if (do_relu) v = fmaxf(v, 0.0f);
      if (residual) v += b2f(residual[(size_t)row*N + col]);
      if (Cf) Cf[(size_t)row*N + col] = v;
      else    C [(size_t)row*N + col] = f2b(v);
    }
  }
}

// ---------------- bf16 GEMM 256x256 tile, 8 waves, 4-phase/K-tile ----------------
// v5: 1 half-tile staged per phase; vmcnt(8) only at p_b/p_d; no manual lgkmcnt
// pins (compiler schedules ds_read->MFMA).  Counted vmcnt asm fences LDS reads
// against async global_load_lds writes; raw s_barrier orders cross-wave.
__global__ __launch_bounds__(512,2) void gemm256(const u16* __restrict__ A, const u16* __restrict__ Bt,
    u16* __restrict__ C, float* __restrict__ Cf, int N, int K,
    const float* __restrict__ bias, const u16* __restrict__ residual, int do_relu, int gx)
{
  __shared__ __align__(16) u16 As[2][256*64];
  __shared__ __align__(16) u16 Bs[2][256*64];
  int t = threadIdx.x;
  int bid = blockIdx.y*gridDim.x + blockIdx.x;
  int xcd = bid & 7, slot = bid >> 3;
  int gy = 8/gx;
  int rx = gridDim.x/gx, ry = gridDim.y/gy;
  int col_b = (xcd%gx)*rx + slot%rx;
  int row_b = (xcd/gx)*ry + slot/rx;
  int row0 = row_b*256, col0 = col_b*256;
  int l = t&63, w = t>>6;
  int wr = w>>2, wc = w&3;           // 2 x 4 wave grid, per-wave 128(M) x 64(N)
  int lr = l&15, lq = l>>4, sw = lr&7;

  f32x4 acc[8][4];
  #pragma unroll
  for (int m=0;m<8;++m)
    #pragma unroll
    for (int n=0;n<4;++n) acc[m][n] = f32x4{0.f,0.f,0.f,0.f};

  int i = t>>3, c8 = t&7;
  int swc = (c8 ^ (i&7))*8;
  const u16* aS[4]; const u16* bS[4];
  {
    int la[4] = { i, 128+i, 64+i, 192+i };
    #pragma unroll
    for (int s=0;s<4;++s){
      aS[s] = A + (size_t)(row0 + la[s])*K + swc;
      int p = s*64 + i;
      int lb = ((p>>5)&3)*64 + (p>>7)*32 + (p&31);
      bS[s] = Bt + (size_t)(col0 + lb)*K + swc;
    }
  }
  int nk = K>>6;   // requires nk >= 3

  u16* A0p = As[0]; u16* A1p = As[1];
  u16* B0p = Bs[0]; u16* B1p = Bs[1];

  short8 af[4][2], bP[2][2], bQ[2][2];

#define VM8  asm volatile("s_waitcnt vmcnt(8)" ::: "memory");
#define VM6  asm volatile("s_waitcnt vmcnt(6)" ::: "memory");
#define VM0  asm volatile("s_waitcnt vmcnt(0)" ::: "memory");
#define BAR  __builtin_amdgcn_s_barrier();

#define RD_A(BUF,qm) \
  _Pragma("unroll") \
  for (int mm=0;mm<4;++mm){ \
    _Pragma("unroll") \
    for (int kk=0;kk<2;++kk) \
      af[mm][kk] = *(const short8*)((const u16*)(BUF) + ((qm)*128 + wr*64 + mm*16 + lr)*64 + (((kk*4+lq)^sw)<<3)); \
  }
#define RD_B(DST,BUF,qn) \
  _Pragma("unroll") \
  for (int nn=0;nn<2;++nn){ \
    _Pragma("unroll") \
    for (int kk=0;kk<2;++kk) \
      DST[nn][kk] = *(const short8*)((const u16*)(BUF) + ((qn)*128 + wc*32 + nn*16 + lr)*64 + (((kk*4+lq)^sw)<<3)); \
  }
#define MMQ(qm,qn,BSS) \
  __builtin_amdgcn_s_setprio(1); \
  _Pragma("unroll") \
  for (int mm=0;mm<4;++mm){ \
    _Pragma("unroll") \
    for (int nn=0;nn<2;++nn){ \
      _Pragma("unroll") \
      for (int kk=0;kk<2;++kk) \
        acc[(qm)*4+mm][(qn)*2+nn] = __builtin_amdgcn_mfma_f32_16x16x32_bf16(af[mm][kk], BSS[nn][kk], acc[(qm)*4+mm][(qn)*2+nn], 0,0,0); \
    } \
  } \
  __builtin_amdgcn_s_setprio(0);

  // prologue: 14 loads — tile0 {A0,B0,B1,A1} -> buf0; tile1 {A0,B0,B1} -> buf1
  async16(aS[0], A0p + 0*4096 + t*8);
  async16(aS[1], A0p + 1*4096 + t*8);
  async16(bS[0], B0p + 0*4096 + t*8);
  async16(bS[1], B0p + 1*4096 + t*8);
  async16(bS[2], B0p + 2*4096 + t*8);
  async16(bS[3], B0p + 3*4096 + t*8);
  async16(aS[2], A0p + 2*4096 + t*8);
  async16(aS[3], A0p + 3*4096 + t*8);
  async16(aS[0]+64, A1p + 0*4096 + t*8);
  async16(aS[1]+64, A1p + 1*4096 + t*8);
  async16(bS[0]+64, B1p + 0*4096 + t*8);
  async16(bS[1]+64, B1p + 1*4096 + t*8);
  async16(bS[2]+64, B1p + 2*4096 + t*8);
  async16(bS[3]+64, B1p + 3*4096 + t*8);
  VM8; BAR;                               // retires tile0 {A0,B0,B1}
  RD_A(A0p, 0); RD_B(bP, B0p, 0);

  for (int kt=0; kt<nk-1; ++kt){
    int cur = kt&1;
    u16* Ac = As[cur]; u16* Bc = Bs[cur];
    u16* An = As[cur^1]; u16* Bn = Bs[cur^1];
    int ko1 = (kt+1)<<6;
    int kc2 = (kt+2 < nk) ? kt+2 : nk-1;
    int ko2 = kc2<<6;
    // p_a: MMQ(0,0); stage A1(k+1)->next buf
    async16(aS[2]+ko1, An + 2*4096 + t*8);
    async16(aS[3]+ko1, An + 3*4096 + t*8);
    BAR;
    MMQ(0,0,bP);
    RD_B(bQ, Bc, 1);
    BAR;
    // p_b: MMQ(0,1); stage B1(k+2)->cur buf; wait
    async16(bS[2]+ko2, Bc + 2*4096 + t*8);
    async16(bS[3]+ko2, Bc + 3*4096 + t*8);
    VM8; BAR;
    MMQ(0,1,bQ);
    RD_A(Ac, 1);
    BAR;
    // p_c: MMQ(1,1); stage A0(k+2)->cur buf
    async16(aS[0]+ko2, Ac + 0*4096 + t*8);
    async16(aS[1]+ko2, Ac + 1*4096 + t*8);
    BAR;
    MMQ(1,1,bQ);
    BAR;
    // p_d: MMQ(1,0); stage B0(k+2)->cur buf; wait; prefetch-read next A0,B0
    async16(bS[0]+ko2, Bc + 0*4096 + t*8);
    async16(bS[1]+ko2, Bc + 1*4096 + t*8);
    VM8; BAR;
    MMQ(1,0,bP);
    RD_A(An, 0); RD_B(bP, Bn, 0);
    BAR;
  }
  { // tail tile (nk-1): no staging
    int cur = (nk-1)&1;
    u16* Ac = As[cur]; u16* Bc = Bs[cur];
    BAR;
    MMQ(0,0,bP);
    RD_B(bQ, Bc, 1);
    BAR;
    VM6; BAR;                             // retires A1(nk-1)
    MMQ(0,1,bQ);
    RD_A(Ac, 1);
    MMQ(1,1,bQ);
    MMQ(1,0,bP);
  }
  VM0;   // drain remaining async LDS writes before epilogue

#undef VM8
#undef VM6
#undef VM0
#undef BAR
#undef RD_A
#undef RD_B
#undef MMQ

  #pragma unroll
  for (int m=0;m<8;++m){
    #pragma unroll
    for (int n=0;n<4;++n){
      int col = col0 + wc*64 + n*16 + lr;
      float bv = bias ? bias[col] : 0.0f;
      #pragma unroll
      for (int r=0;r<4;++r){
        int row = row0 + wr*128 + m*16 + lq*4 + r;
        float v = acc[m][n][r] + bv;
        if (do_relu) v = fmaxf(v, 0.0f);
        if (residual) v += b2f(residual[(size_t)row*N + col]);
        if (Cf) Cf[(size_t)row*N + col] = v;
        else    C [(size_t)row*N + col] = f2b(v);
      }
    }
  }
}

// ---------------- causal flash attention v5: Q-tile 128, 2 q-sets per wave ----------------
// Each staged K/V s-tile now serves 128 q rows (was 64): staging volume and
// V-reads halve, K-reads halve (one kf pair feeds both sets' S^T), at identical
// MFMA count — ~1.95x less LDS+L2 traffic per FLOP.  4 waves; wave w owns rows
// Qb+w*16 (set0) and Qb+64+w*16 (set1).  Set-serial softmax (S0 freed before S1
// softmax) keeps regs bounded; launch_bounds(256,2) guarantees no spill.
// grid 512 = 2 blocks/CU; qt keyed on grp bit1 so CU slot pairs (slot,slot+32)
// sum to constant work.  Final iteration's set0 is fully masked (p=0, alpha=1,
// exact) — ~5% waste for uniform control flow.
__global__ __launch_bounds__(256,2) void attn_kernel(const u16* __restrict__ QKV,
    const u16* __restrict__ VT, u16* __restrict__ O)
{
  const int T=2048, LD=3072, E=1024;
  int bid = blockIdx.y * gridDim.x + blockIdx.x;
  int xcd = bid & 7, slot = bid >> 3;      // 64 slots per xcd
  int idx = slot & 15, grp = slot >> 4;    // 4 heads per xcd
  int qt = ((grp>>1)&1) ? idx : 15 - idx;  // (slot, slot+32) -> constant work
  int bh = xcd*4 + grp;
  int bb = bh>>4, h = bh&15;
  const u16* base = QKV + (size_t)bb*T*LD;
  const u16* Qp = base + h*64;
  const u16* Kp = base + 1024 + h*64;
  const u16* Vtp = VT + (size_t)bh*64*2048;
  int t = threadIdx.x, l = t&63, w = t>>6;
  int lr = l&15, lq = l>>4;

  __shared__ __align__(16) u16 Ks[2][64*64];   // [s][d], chunk c at slot c^(s&7)
  __shared__ __align__(16) u16 Vs[2][64*64];   // [d][s], chunk c at slot c^(d&7)

  const float QSC = 0.125f*1.44269504f;
  int q0 = qt*128 + w*16;
  short8 aq0[2], aq1[2];
  #pragma unroll
  for (int kk=0;kk<2;++kk){
    short8 r0 = *(const short8*)(Qp + (size_t)(q0+lr)*LD    + kk*32 + lq*8);
    short8 r1 = *(const short8*)(Qp + (size_t)(q0+64+lr)*LD + kk*32 + lq*8);
    short8 s0v, s1v;
    #pragma unroll
    for (int j=0;j<8;++j){
      s0v[j] = (short)f2b(b2f((u16)r0[j])*QSC);
      s1v[j] = (short)f2b(b2f((u16)r1[j])*QSC);
    }
    aq0[kk]=s0v; aq1[kk]=s1v;
  }

  float mrun0 = -3e38f, lrun0 = 0.f;
  float mrun1 = -3e38f, lrun1 = 0.f;
  f32x4 O0[4], O1[4];
  #pragma unroll
  for (int dt=0;dt<4;++dt){ O0[dt] = f32x4{0.f,0.f,0.f,0.f}; O1[dt] = f32x4{0.f,0.f,0.f,0.f}; }

  int kc = (l&7) ^ (l>>3);
  int ra = 8*w + (l>>3);

  // prologue: stage tile 0
  async16(Kp  + (size_t)ra*LD        + kc*8, Ks[0] + t*8);
  async16(Kp  + (size_t)(ra+32)*LD   + kc*8, Ks[0] + 2048 + t*8);
  async16(Vtp + (size_t)ra*2048      + kc*8, Vs[0] + t*8);
  async16(Vtp + (size_t)(ra+32)*2048 + kc*8, Vs[0] + 2048 + t*8);

  int itmax = 2*qt + 1;
  for (int it=0; it<=itmax; ++it){
    int s0 = it*64, cur = it&1;
    __syncthreads();
    if (it < itmax){
      int sn = s0+64;
      u16* kd = Ks[cur^1]; u16* vd = Vs[cur^1];
      async16(Kp  + (size_t)(sn+ra)*LD        + kc*8, kd + t*8);
      async16(Kp  + (size_t)(sn+ra+32)*LD     + kc*8, kd + 2048 + t*8);
      async16(Vtp + (size_t)ra*2048      + sn + kc*8, vd + t*8);
      async16(Vtp + (size_t)(ra+32)*2048 + sn + kc*8, vd + 2048 + t*8);
    }
    const u16* ks = Ks[cur];
    const u16* vs = Vs[cur];

    // S^T[s][q] for both q-sets off one kf read pair
    f32x4 S0[4], S1[4];
    #pragma unroll
    for (int st=0; st<4; ++st){
      short8 kf0 = *(const short8*)(ks + (st*16+lr)*64 + ((lq  )^(lr&7))*8);
      short8 kf1 = *(const short8*)(ks + (st*16+lr)*64 + ((4+lq)^(lr&7))*8);
      f32x4 z0 = f32x4{0.f,0.f,0.f,0.f};
      f32x4 z1 = f32x4{0.f,0.f,0.f,0.f};
      z0 = __builtin_amdgcn_mfma_f32_16x16x32_bf16(kf0, aq0[0], z0, 0,0,0);
      z0 = __builtin_amdgcn_mfma_f32_16x16x32_bf16(kf1, aq0[1], z0, 0,0,0);
      z1 = __builtin_amdgcn_mfma_f32_16x16x32_bf16(kf0, aq1[0], z1, 0,0,0);
      z1 = __builtin_amdgcn_mfma_f32_16x16x32_bf16(kf1, aq1[1], z1, 0,0,0);
      S0[st] = z0; S1[st] = z1;
    }
    // masking: set0 diag at it==2qt, fully masked at it==itmax (same formula)
    if (it >= 2*qt){
      int qg = q0 + lr;
      #pragma unroll
      for (int st=0;st<4;++st)
        #pragma unroll
        for (int r=0;r<4;++r){
          int sg = s0 + st*16 + lq*4 + r;
          if (sg > qg) S0[st][r] = -3e38f;
        }
    }
    if (it == itmax){
      int qg = q0 + 64 + lr;
      #pragma unroll
      for (int st=0;st<4;++st)
        #pragma unroll
        for (int r=0;r<4;++r){
          int sg = s0 + st*16 + lq*4 + r;
          if (sg > qg) S1[st][r] = -3e38f;
        }
    }
    short4_t pk0[4], pk1[4];
    // softmax set 0
    {
      float m = S0[0][0];
      #pragma unroll
      for (int st=0;st<4;++st)
        #pragma unroll
        for (int r=0;r<4;++r) m = fmaxf(m, S0[st][r]);
      m = fmaxf(m, __shfl_xor(m,16));
      m = fmaxf(m, __shfl_xor(m,32));
      float mnew = fmaxf(mrun0, m);
      float alpha = EXP2F(mrun0 - mnew);
      mrun0 = mnew;
      float ssum = 0.f;
      #pragma unroll
      for (int st=0;st<4;++st)
        #pragma unroll
        for (int r=0;r<4;++r){ float p = EXP2F(S0[st][r]-mnew); S0[st][r]=p; ssum+=p; }
      ssum += __shfl_xor(ssum,16);
      ssum += __shfl_xor(ssum,32);
      lrun0 = lrun0*alpha + ssum;
      #pragma unroll
      for (int st=0;st<4;++st) pk0[st] = pack4(S0[st]);
      float af[4];
      #pragma unroll
      for (int r=0;r<4;++r) af[r] = __shfl(alpha, lq*4+r);
      #pragma unroll
      for (int dt=0;dt<4;++dt)
        #pragma unroll
        for (int r=0;r<4;++r) O0[dt][r] *= af[r];
    }
    // softmax set 1
    {
      float m = S1[0][0];
      #pragma unroll
      for (int st=0;st<4;++st)
        #pragma unroll
        for (int r=0;r<4;++r) m = fmaxf(m, S1[st][r]);
      m = fmaxf(m, __shfl_xor(m,16));
      m = fmaxf(m, __shfl_xor(m,32));
      float mnew = fmaxf(mrun1, m);
      float alpha = EXP2F(mrun1 - mnew);
      mrun1 = mnew;
      float ssum = 0.f;
      #pragma unroll
      for (int st=0;st<4;++st)
        #pragma unroll
        for (int r=0;r<4;++r){ float p = EXP2F(S1[st][r]-mnew); S1[st][r]=p; ssum+=p; }
      ssum += __shfl_xor(ssum,16);
      ssum += __shfl_xor(ssum,32);
      lrun1 = lrun1*alpha + ssum;
      #pragma unroll
      for (int st=0;st<4;++st) pk1[st] = pack4(S1[st]);
      float af[4];
      #pragma unroll
      for (int r=0;r<4;++r) af[r] = __shfl(alpha, lq*4+r);
      #pragma unroll
      for (int dt=0;dt<4;++dt)
        #pragma unroll
        for (int r=0;r<4;++r) O1[dt][r] *= af[r];
    }
    // PV: shared vf feeds both sets
    #pragma unroll
    for (int st=0;st<4;++st){
      #pragma unroll
      for (int dt=0;dt<4;++dt){
        short4_t vf = *(const short4_t*)(vs + (dt*16+lr)*64 + ((2*st+(lq>>1))^(lr&7))*8 + (lq&1)*4);
        O0[dt] = MFMA16(pk0[st], vf, O0[dt]);
        O1[dt] = MFMA16(pk1[st], vf, O1[dt]);
      }
    }
  }
  float linv0[4], linv1[4];
  #pragma unroll
  for (int r=0;r<4;++r){
    linv0[r] = 1.0f/__shfl(lrun0, lq*4+r);
    linv1[r] = 1.0f/__shfl(lrun1, lq*4+r);
  }
  #pragma unroll
  for (int dt=0;dt<4;++dt)
    #pragma unroll
    for (int r=0;r<4;++r){
      int qa = q0 + lq*4 + r;
      int qb = q0 + 64 + lq*4 + r;
      O[(size_t)(bb*T+qa)*E + h*64 + dt*16 + lr] = f2b(O0[dt][r]*linv0[r]);
      O[(size_t)(bb*T+qb)*E + h*64 + dt*16 + lr] = f2b(O1[dt][r]*linv1[r]);
    }
}

// ---------------- host ----------------
extern "C" void kernel_launch(void* const* d_in, const int* in_sizes, int n_in,
                              void* d_out, int out_size, void* d_ws, size_t ws_size,
                              hipStream_t stream)
{
  (void)in_sizes; (void)n_in; (void)out_size; (void)ws_size;
  const float* x     = (const float*)d_in[0];
  const float* wq    = (const float*)d_in[1];
  const float* wk    = (const float*)d_in[2];
  const float* wv    = (const float*)d_in[3];
  const float* wproj = (const float*)d_in[4];
  const float* bproj = (const float*)d_in[5];
  const float* g1    = (const float*)d_in[6];
  const float* be1   = (const float*)d_in[7];
  const float* g2    = (const float*)d_in[8];
  const float* be2   = (const float*)d_in[9];
  const float* w1    = (const float*)d_in[10];
  const float* b1    = (const float*)d_in[11];
  const float* w2    = (const float*)d_in[12];
  const float* b2    = (const float*)d_in[13];
  float* out = (float*)d_out;

  char* ws = (char*)d_ws;
  size_t off = 0;
  auto alloc = [&](size_t bytes)->void*{ void* p = ws + off; off += (bytes + 255) & ~(size_t)255; return p; };
  u16* hnorm  = (u16*)alloc((size_t)4096*1024*2);
  u16* qkv    = (u16*)alloc((size_t)4096*3072*2);
  u16* VT     = (u16*)alloc((size_t)32*64*2048*2);
  u16* attnO  = (u16*)alloc((size_t)4096*1024*2);
  u16* x2     = (u16*)alloc((size_t)4096*1024*2);
  u16* h2     = (u16*)alloc((size_t)4096*1024*2);
  u16* ffn1   = (u16*)alloc((size_t)4096*4096*2);
  u16* wqkvT  = (u16*)alloc((size_t)3072*1024*2);
  u16* wprojT = (u16*)alloc((size_t)1024*1024*2);
  u16* w1T    = (u16*)alloc((size_t)4096*1024*2);
  u16* w2T    = (u16*)alloc((size_t)1024*4096*2);

  qkv_repack  <<<dim3(16,48),256,0,stream>>>(wq,wk,wv,wqkvT);
  transpose_bt<<<dim3(16,16),256,0,stream>>>(wproj, wprojT, 1024, 1024);
  transpose_bt<<<dim3(64,16),256,0,stream>>>(w1,    w1T,    4096, 1024);
  transpose_bt<<<dim3(16,64),256,0,stream>>>(w2,    w2T,    1024, 4096);

  ln_kernel<1><<<4096,256,0,stream>>>(x, g1, be1, hnorm);
  gemm256<<<dim3(12,16),512,0,stream>>>(hnorm, wqkvT, qkv, nullptr, 3072, 1024, nullptr, nullptr, 0, 4);
  vtrans<<<dim3(32,32),256,0,stream>>>(qkv, VT);
  attn_kernel<<<dim3(16,32),256,0,stream>>>(qkv, VT, attnO);
  gemm64<<<dim3(16,64),256,0,stream>>>(attnO, wprojT, x2, nullptr, 4096,1024,1024, bproj, hnorm, 0, 4);
  ln_kernel<0><<<4096,256,0,stream>>>(x2, g2, be2, h2);
  gemm256<<<dim3(16,16),512,0,stream>>>(h2, w1T, ffn1, nullptr, 4096, 1024, b1, nullptr, 1, 4);
  gemm64<<<dim3(16,64),256,0,stream>>>(ffn1, w2T, nullptr, out, 4096,1024,4096, b2, h2, 0, 4);
}

// Round 13
// 342.833 us; speedup vs baseline: 1.0438x; 1.0438x over previous
//
#include <hip/hip_runtime.h>
#include <stdint.h>

typedef unsigned short u16;
typedef __attribute__((ext_vector_type(8))) short short8;
typedef __attribute__((ext_vector_type(4))) short short4_t;
typedef __attribute__((ext_vector_type(4))) float f32x4;

__device__ __forceinline__ float b2f(u16 u){ union{unsigned i; float f;}v; v.i=((unsigned)u)<<16; return v.f; }
__device__ __forceinline__ u16 f2b(float f){ unsigned x=__float_as_uint(f); return (u16)((x + 0x7fffu + ((x>>16)&1u))>>16); }

#if __has_builtin(__builtin_amdgcn_exp2f)
#define EXP2F(x) __builtin_amdgcn_exp2f(x)
#else
#define EXP2F(x) exp2f(x)
#endif

#if __has_builtin(__builtin_amdgcn_mfma_f32_16x16x16_bf16)
#define MFMA16(a,b,c) __builtin_amdgcn_mfma_f32_16x16x16_bf16(a,b,c,0,0,0)
#elif __has_builtin(__builtin_amdgcn_mfma_f32_16x16x16bf16_1k)
#define MFMA16(a,b,c) __builtin_amdgcn_mfma_f32_16x16x16bf16_1k(a,b,c,0,0,0)
#else
static __device__ __forceinline__ f32x4 mfma16_asm(short4_t a, short4_t b, f32x4 c){
  __asm__("v_mfma_f32_16x16x16_bf16 %0, %1, %2, %3" : "=v"(c) : "v"(a), "v"(b), "0"(c));
  return c;
}
#define MFMA16(a,b,c) mfma16_asm(a,b,c)
#endif

__device__ __forceinline__ void async16(const void* g, void* l){
  __builtin_amdgcn_global_load_lds((const __attribute__((address_space(1))) void*)g,
                                   (__attribute__((address_space(3))) void*)l, 16, 0, 0);
}

// pack 4 fp32 (in [0,1]) -> 4 bf16 (round-half-up) as K=16 A-fragment regs
__device__ __forceinline__ short4_t pack4(f32x4 s){
  unsigned u0 = (__float_as_uint(s[0]) + 0x8000u) >> 16;
  unsigned u1 = (__float_as_uint(s[1]) + 0x8000u) & 0xffff0000u;
  unsigned u2 = (__float_as_uint(s[2]) + 0x8000u) >> 16;
  unsigned u3 = (__float_as_uint(s[3]) + 0x8000u) & 0xffff0000u;
  union { unsigned v[2]; short4_t s4; } r;
  r.v[0] = u0 | u1; r.v[1] = u2 | u3;
  return r.s4;
}

// ---------------- LayerNorm (E=1024, one block per row) ----------------
template<int IN_F32>
__global__ __launch_bounds__(256) void ln_kernel(const void* __restrict__ xin,
    const float* __restrict__ g, const float* __restrict__ b, u16* __restrict__ y)
{
  const int E = 1024;
  int row = blockIdx.x, t = threadIdx.x;
  float f0,f1,f2,f3;
  if (IN_F32){
    const float* xr = (const float*)xin + (size_t)row*E;
    float4 xv = *(const float4*)(xr + t*4);
    f0=xv.x; f1=xv.y; f2=xv.z; f3=xv.w;
  } else {
    const u16* xr = (const u16*)xin + (size_t)row*E;
    ushort4 xv = *(const ushort4*)(xr + t*4);
    f0=b2f(xv.x); f1=b2f(xv.y); f2=b2f(xv.z); f3=b2f(xv.w);
  }
  float s1 = f0+f1+f2+f3;
  float s2 = f0*f0+f1*f1+f2*f2+f3*f3;
  #pragma unroll
  for (int off=32; off>=1; off>>=1){ s1 += __shfl_xor(s1,off); s2 += __shfl_xor(s2,off); }
  __shared__ float red[8];
  int w = t>>6;
  if ((t&63)==0){ red[w]=s1; red[4+w]=s2; }
  __syncthreads();
  float S1 = red[0]+red[1]+red[2]+red[3];
  float S2 = red[4]+red[5]+red[6]+red[7];
  float mean = S1*(1.0f/E);
  float var  = S2*(1.0f/E) - mean*mean;
  float inv  = rsqrtf(var + 1e-5f);
  float4 gv = *(const float4*)(g + t*4);
  float4 bv = *(const float4*)(b + t*4);
  ushort4 o;
  o.x = f2b((f0-mean)*inv*gv.x+bv.x);
  o.y = f2b((f1-mean)*inv*gv.y+bv.y);
  o.z = f2b((f2-mean)*inv*gv.z+bv.z);
  o.w = f2b((f3-mean)*inv*gv.w+bv.w);
  *(ushort4*)(y + (size_t)row*E + t*4) = o;
}

// ---------------- fp32->bf16 64x64-tiled transpose ----------------
__global__ __launch_bounds__(256) void transpose_bt(const float* __restrict__ src, u16* __restrict__ dst,
                                                    int ld_src, int ld_dst)
{
  __shared__ u16 tile[64*66];
  int c0 = blockIdx.x*64, r0 = blockIdx.y*64;
  int t = threadIdx.x;
  #pragma unroll
  for (int i=0;i<16;++i){
    int lin = i*256 + t;
    int rr = lin>>6, cc = lin&63;
    tile[cc*66+rr] = f2b(src[(size_t)(r0+rr)*ld_src + c0+cc]);
  }
  __syncthreads();
  #pragma unroll
  for (int i=0;i<16;++i){
    int lin = i*256 + t;
    int cc = lin>>6, rr = lin&63;
    dst[(size_t)(c0+cc)*ld_dst + r0+rr] = tile[cc*66+rr];
  }
}

// ---------------- QKV weight repack ----------------
__global__ __launch_bounds__(256) void qkv_repack(const float* __restrict__ wq, const float* __restrict__ wk,
                                                  const float* __restrict__ wv, u16* __restrict__ dst)
{
  __shared__ u16 tile[64*66];
  int e0 = blockIdx.x*64;
  int sel = blockIdx.y>>4, h = blockIdx.y&15;
  const float* src = (sel==0?wq:(sel==1?wk:wv)) + (size_t)h*1024*64;
  int t = threadIdx.x;
  #pragma unroll
  for (int i=0;i<16;++i){
    int lin=i*256+t; int rr=lin>>6, cc=lin&63;
    tile[cc*66+rr] = f2b(src[(size_t)(e0+rr)*64 + cc]);
  }
  __syncthreads();
  #pragma unroll
  for (int i=0;i<16;++i){
    int lin=i*256+t; int cc=lin>>6, rr=lin&63;
    dst[(size_t)(sel*1024 + h*64 + cc)*1024 + e0+rr] = tile[cc*66+rr];
  }
}

// ---------------- V transpose: qkv V-slice -> VT[bh][64][2048] ----------------
__global__ __launch_bounds__(256) void vtrans(const u16* __restrict__ qkv, u16* __restrict__ VT)
{
  __shared__ u16 tile[64*66];
  int bh = blockIdx.y, bb = bh>>4, h = bh&15;
  int s0 = blockIdx.x*64;
  const u16* src = qkv + ((size_t)(bb*2048) + s0)*3072 + 2048 + h*64;
  int t = threadIdx.x;
  int sr = t>>3, c0 = (t&7)*8;
  #pragma unroll
  for (int half=0; half<2; ++half){
    const u16* p = src + (size_t)(sr+half*32)*3072 + c0;
    ushort4 v0 = *(const ushort4*)p;
    ushort4 v1 = *(const ushort4*)(p+4);
    uint* d = (uint*)(tile + (sr+half*32)*66 + c0);
    d[0] = (uint)v0.x | ((uint)v0.y<<16);
    d[1] = (uint)v0.z | ((uint)v0.w<<16);
    d[2] = (uint)v1.x | ((uint)v1.y<<16);
    d[3] = (uint)v1.z | ((uint)v1.w<<16);
  }
  __syncthreads();
  u16* out = VT + (size_t)bh*64*2048 + s0;
  int dw = t>>3, sc = (t&7)*8;
  #pragma unroll
  for (int half=0; half<2; ++half){
    int d = dw + half*32;
    short8 pk;
    #pragma unroll
    for (int j=0;j<8;++j) pk[j] = (short)tile[(sc+j)*66 + d];
    *(short8*)(out + (size_t)d*2048 + sc) = pk;
  }
}

// ---------------- gemm64: 64x64 tile, 4 waves, high-TLP (4 blocks/CU) ----------------
// For N=1024 shapes (FFN2, proj): 1024 blocks = 4 blocks/CU = 16 waves/CU.
// r10 measured: FFN2 64.5 -> 59.9us, occupancy 19.8 -> 37.5%.
__global__ __launch_bounds__(256, 4) void gemm64(const u16* __restrict__ A, const u16* __restrict__ Bt,
    u16* __restrict__ C, float* __restrict__ Cf, int M, int N, int K,
    const float* __restrict__ bias, const u16* __restrict__ residual, int do_relu, int gx)
{
  __shared__ __align__(16) u16 As[2][64*64];
  __shared__ __align__(16) u16 Bs[2][64*64];
  int t = threadIdx.x;
  int bid = blockIdx.y * gridDim.x + blockIdx.x;
  int xcd = bid & 7, slot = bid >> 3;
  int gy = 8 / gx;
  int rx = gridDim.x / gx, ry = gridDim.y / gy;
  int col_b = (xcd % gx) * rx + (slot % rx);
  int row_b = (xcd / gx) * ry + (slot / rx);
  int row0 = row_b*64, col0 = col_b*64;
  int l = t&63, w = t>>6;
  int lr = l&15, lq = l>>4;
  (void)M;

  f32x4 acc[4];
  #pragma unroll
  for (int j=0;j<4;++j) acc[j] = f32x4{0.f,0.f,0.f,0.f};

  const u16* gA = A  + (size_t)(row0 + (t>>3))*K + (((t&7)^((t>>3)&7))<<3);
  const u16* gB = Bt + (size_t)(col0 + (t>>3))*K + (((t&7)^((t>>3)&7))<<3);
  const size_t rnd = (size_t)32*K;
  int nk = K>>6;

  #pragma unroll
  for (int r=0;r<2;++r){
    async16(gA + r*rnd, As[0] + r*2048 + t*8);
    async16(gB + r*rnd, Bs[0] + r*2048 + t*8);
  }

  int sw8 = (lr&7);
  for (int kt=0; kt<nk; ++kt){
    int cur = kt&1;
    __syncthreads();
    if (kt+1 < nk){
      int ko = (kt+1)<<6;
      #pragma unroll
      for (int r=0;r<2;++r){
        async16(gA + r*rnd + ko, As[cur^1] + r*2048 + t*8);
        async16(gB + r*rnd + ko, Bs[cur^1] + r*2048 + t*8);
      }
    }
    const u16* as = As[cur];
    const u16* bs = Bs[cur];
    #pragma unroll
    for (int kk=0;kk<2;++kk){
      int so = (((kk*4+lq)^sw8))<<3;
      short8 a = *(const short8*)(as + (w*16+lr)*64 + so);
      short8 b[4];
      #pragma unroll
      for (int j=0;j<4;++j) b[j] = *(const short8*)(bs + (j*16+lr)*64 + so);
      #pragma unroll
      for (int j=0;j<4;++j)
        acc[j] = __builtin_amdgcn_mfma_f32_16x16x32_bf16(a, b[j], acc[j], 0,0,0);
    }
  }

  #pragma unroll
  for (int j=0;j<4;++j){
    int col = col0 + j*16 + lr;
    float bv = bias ? bias[col] : 0.0f;
    #pragma unroll
    for (int r=0;r<4;++r){
      int row = row0 + w*16 + lq*4 + r;
      float v = acc[j][r] + bv;
      if (do_relu) v = fmaxf(v, 0.0f);
      if (residual) v += b2f(residual[(size_t)row*N + col]);
      if (Cf) Cf[(size_t)row*N + col] = v;
      else    C [(size_t)row*N + col] = f2b(v);
    }
  }
}

// ---------------- bf16 GEMM 256x256 tile, 8 waves, 4-phase/K-tile ----------------
// v5: 1 half-tile staged per phase; vmcnt(8) only at p_b/p_d; no manual lgkmcnt
// pins (compiler schedules ds_read->MFMA).  Counted vmcnt asm fences LDS reads
// against async global_load_lds writes; raw s_barrier orders cross-wave.
__global__ __launch_bounds__(512,2) void gemm256(const u16* __restrict__ A, const u16* __restrict__ Bt,
    u16* __restrict__ C, float* __restrict__ Cf, int N, int K,
    const float* __restrict__ bias, const u16* __restrict__ residual, int do_relu, int gx)
{
  __shared__ __align__(16) u16 As[2][256*64];
  __shared__ __align__(16) u16 Bs[2][256*64];
  int t = threadIdx.x;
  int bid = blockIdx.y*gridDim.x + blockIdx.x;
  int xcd = bid & 7, slot = bid >> 3;
  int gy = 8/gx;
  int rx = gridDim.x/gx, ry = gridDim.y/gy;
  int col_b = (xcd%gx)*rx + slot%rx;
  int row_b = (xcd/gx)*ry + slot/rx;
  int row0 = row_b*256, col0 = col_b*256;
  int l = t&63, w = t>>6;
  int wr = w>>2, wc = w&3;           // 2 x 4 wave grid, per-wave 128(M) x 64(N)
  int lr = l&15, lq = l>>4, sw = lr&7;

  f32x4 acc[8][4];
  #pragma unroll
  for (int m=0;m<8;++m)
    #pragma unroll
    for (int n=0;n<4;++n) acc[m][n] = f32x4{0.f,0.f,0.f,0.f};

  int i = t>>3, c8 = t&7;
  int swc = (c8 ^ (i&7))*8;
  const u16* aS[4]; const u16* bS[4];
  {
    int la[4] = { i, 128+i, 64+i, 192+i };
    #pragma unroll
    for (int s=0;s<4;++s){
      aS[s] = A + (size_t)(row0 + la[s])*K + swc;
      int p = s*64 + i;
      int lb = ((p>>5)&3)*64 + (p>>7)*32 + (p&31);
      bS[s] = Bt + (size_t)(col0 + lb)*K + swc;
    }
  }
  int nk = K>>6;   // requires nk >= 3

  u16* A0p = As[0]; u16* A1p = As[1];
  u16* B0p = Bs[0]; u16* B1p = Bs[1];

  short8 af[4][2], bP[2][2], bQ[2][2];

#define VM8  asm volatile("s_waitcnt vmcnt(8)" ::: "memory");
#define VM6  asm volatile("s_waitcnt vmcnt(6)" ::: "memory");
#define VM0  asm volatile("s_waitcnt vmcnt(0)" ::: "memory");
#define BAR  __builtin_amdgcn_s_barrier();

#define RD_A(BUF,qm) \
  _Pragma("unroll") \
  for (int mm=0;mm<4;++mm){ \
    _Pragma("unroll") \
    for (int kk=0;kk<2;++kk) \
      af[mm][kk] = *(const short8*)((const u16*)(BUF) + ((qm)*128 + wr*64 + mm*16 + lr)*64 + (((kk*4+lq)^sw)<<3)); \
  }
#define RD_B(DST,BUF,qn) \
  _Pragma("unroll") \
  for (int nn=0;nn<2;++nn){ \
    _Pragma("unroll") \
    for (int kk=0;kk<2;++kk) \
      DST[nn][kk] = *(const short8*)((const u16*)(BUF) + ((qn)*128 + wc*32 + nn*16 + lr)*64 + (((kk*4+lq)^sw)<<3)); \
  }
#define MMQ(qm,qn,BSS) \
  __builtin_amdgcn_s_setprio(1); \
  _Pragma("unroll") \
  for (int mm=0;mm<4;++mm){ \
    _Pragma("unroll") \
    for (int nn=0;nn<2;++nn){ \
      _Pragma("unroll") \
      for (int kk=0;kk<2;++kk) \
        acc[(qm)*4+mm][(qn)*2+nn] = __builtin_amdgcn_mfma_f32_16x16x32_bf16(af[mm][kk], BSS[nn][kk], acc[(qm)*4+mm][(qn)*2+nn], 0,0,0); \
    } \
  } \
  __builtin_amdgcn_s_setprio(0);

  // prologue: 14 loads — tile0 {A0,B0,B1,A1} -> buf0; tile1 {A0,B0,B1} -> buf1
  async16(aS[0], A0p + 0*4096 + t*8);
  async16(aS[1], A0p + 1*4096 + t*8);
  async16(bS[0], B0p + 0*4096 + t*8);
  async16(bS[1], B0p + 1*4096 + t*8);
  async16(bS[2], B0p + 2*4096 + t*8);
  async16(bS[3], B0p + 3*4096 + t*8);
  async16(aS[2], A0p + 2*4096 + t*8);
  async16(aS[3], A0p + 3*4096 + t*8);
  async16(aS[0]+64, A1p + 0*4096 + t*8);
  async16(aS[1]+64, A1p + 1*4096 + t*8);
  async16(bS[0]+64, B1p + 0*4096 + t*8);
  async16(bS[1]+64, B1p + 1*4096 + t*8);
  async16(bS[2]+64, B1p + 2*4096 + t*8);
  async16(bS[3]+64, B1p + 3*4096 + t*8);
  VM8; BAR;                               // retires tile0 {A0,B0,B1}
  RD_A(A0p, 0); RD_B(bP, B0p, 0);

  for (int kt=0; kt<nk-1; ++kt){
    int cur = kt&1;
    u16* Ac = As[cur]; u16* Bc = Bs[cur];
    u16* An = As[cur^1]; u16* Bn = Bs[cur^1];
    int ko1 = (kt+1)<<6;
    int kc2 = (kt+2 < nk) ? kt+2 : nk-1;
    int ko2 = kc2<<6;
    // p_a: MMQ(0,0); stage A1(k+1)->next buf
    async16(aS[2]+ko1, An + 2*4096 + t*8);
    async16(aS[3]+ko1, An + 3*4096 + t*8);
    BAR;
    MMQ(0,0,bP);
    RD_B(bQ, Bc, 1);
    BAR;
    // p_b: MMQ(0,1); stage B1(k+2)->cur buf; wait
    async16(bS[2]+ko2, Bc + 2*4096 + t*8);
    async16(bS[3]+ko2, Bc + 3*4096 + t*8);
    VM8; BAR;
    MMQ(0,1,bQ);
    RD_A(Ac, 1);
    BAR;
    // p_c: MMQ(1,1); stage A0(k+2)->cur buf
    async16(aS[0]+ko2, Ac + 0*4096 + t*8);
    async16(aS[1]+ko2, Ac + 1*4096 + t*8);
    BAR;
    MMQ(1,1,bQ);
    BAR;
    // p_d: MMQ(1,0); stage B0(k+2)->cur buf; wait; prefetch-read next A0,B0
    async16(bS[0]+ko2, Bc + 0*4096 + t*8);
    async16(bS[1]+ko2, Bc + 1*4096 + t*8);
    VM8; BAR;
    MMQ(1,0,bP);
    RD_A(An, 0); RD_B(bP, Bn, 0);
    BAR;
  }
  { // tail tile (nk-1): no staging
    int cur = (nk-1)&1;
    u16* Ac = As[cur]; u16* Bc = Bs[cur];
    BAR;
    MMQ(0,0,bP);
    RD_B(bQ, Bc, 1);
    BAR;
    VM6; BAR;                             // retires A1(nk-1)
    MMQ(0,1,bQ);
    RD_A(Ac, 1);
    MMQ(1,1,bQ);
    MMQ(1,0,bP);
  }
  VM0;   // drain remaining async LDS writes before epilogue

#undef VM8
#undef VM6
#undef VM0
#undef BAR
#undef RD_A
#undef RD_B
#undef MMQ

  #pragma unroll
  for (int m=0;m<8;++m){
    #pragma unroll
    for (int n=0;n<4;++n){
      int col = col0 + wc*64 + n*16 + lr;
      float bv = bias ? bias[col] : 0.0f;
      #pragma unroll
      for (int r=0;r<4;++r){
        int row = row0 + wr*128 + m*16 + lq*4 + r;
        float v = acc[m][n][r] + bv;
        if (do_relu) v = fmaxf(v, 0.0f);
        if (residual) v += b2f(residual[(size_t)row*N + col]);
        if (Cf) Cf[(size_t)row*N + col] = v;
        else    C [(size_t)row*N + col] = f2b(v);
      }
    }
  }
}

// ---------------- causal flash attention v6: Q-tile 128, 8 waves, grid 512 ----------------
// v5 lesson (measured): halving traffic at half the waves/CU LOSES (65.5us, occ 12%,
// HBM 4% — latency-bound).  v6 keeps the traffic halving (one staged 64x64 K/V tile
// serves 128 q rows) but restores v4's 16 waves/CU: 512 threads / 8 waves, wave w
// owns q rows qt*128 + w*16 (one set/wave -> v4 register budget).  Staging: one
// async16 per K/V tile (512 threads x 16B = 8KB).  itmax = 2qt+1; general mask
// (sg>qg) applied for it >= 2*qt — exact for all waves (fully-masked tiles give
// ssum=0, alpha=1); ~3% MFMA waste.  Slot pairs (s,s+32) per CU sum to constant
// work via qt keyed on grp bit1.
__global__ __launch_bounds__(512,4) void attn_kernel(const u16* __restrict__ QKV,
    const u16* __restrict__ VT, u16* __restrict__ O)
{
  const int T=2048, LD=3072, E=1024;
  int bid = blockIdx.y * gridDim.x + blockIdx.x;
  int xcd = bid & 7, slot = bid >> 3;      // 64 slots per xcd
  int idx = slot & 15, grp = slot >> 4;    // 4 heads per xcd
  int qt = ((grp>>1)&1) ? idx : 15 - idx;  // (slot, slot+32) -> constant work
  int bh = xcd*4 + grp;
  int bb = bh>>4, h = bh&15;
  const u16* base = QKV + (size_t)bb*T*LD;
  const u16* Qp = base + h*64;
  const u16* Kp = base + 1024 + h*64;
  const u16* Vtp = VT + (size_t)bh*64*2048;
  int t = threadIdx.x, l = t&63, w = t>>6;   // w in 0..7
  int lr = l&15, lq = l>>4;

  __shared__ __align__(16) u16 Ks[2][64*64];   // [s][d], chunk c at slot c^(s&7)
  __shared__ __align__(16) u16 Vs[2][64*64];   // [d][s], chunk c at slot c^(d&7)

  const float QSC = 0.125f*1.44269504f;
  int q0 = qt*128 + w*16;
  short8 aq[2];
  #pragma unroll
  for (int kk=0;kk<2;++kk){
    short8 raw = *(const short8*)(Qp + (size_t)(q0+lr)*LD + kk*32 + lq*8);
    short8 sc;
    #pragma unroll
    for (int j=0;j<8;++j) sc[j] = (short)f2b(b2f((u16)raw[j])*QSC);
    aq[kk]=sc;
  }

  float mrun = -3e38f, lrun = 0.f;
  f32x4 Oacc[4];
  #pragma unroll
  for (int dt=0;dt<4;++dt) Oacc[dt] = f32x4{0.f,0.f,0.f,0.f};

  // staging map (512 threads): row ra = 8w + (l>>3) covers 0..63; phys chunk l&7;
  // source chunk kc = (l&7)^(ra&7); LDS dest t*8 == ra*64 + (l&7)*8.
  int kc = (l&7) ^ (l>>3);
  int ra = 8*w + (l>>3);

  // prologue: stage tile 0 (one call per K/V tile)
  async16(Kp  + (size_t)ra*LD   + kc*8, Ks[0] + t*8);
  async16(Vtp + (size_t)ra*2048 + kc*8, Vs[0] + t*8);

  int itmax = 2*qt + 1;
  for (int it=0; it<=itmax; ++it){
    int s0 = it*64, cur = it&1;
    __syncthreads();
    if (it < itmax){
      int sn = s0+64;
      async16(Kp  + (size_t)(sn+ra)*LD   + kc*8, Ks[cur^1] + t*8);
      async16(Vtp + (size_t)ra*2048 + sn + kc*8, Vs[cur^1] + t*8);
    }
    const u16* ks = Ks[cur];
    const u16* vs = Vs[cur];

    // S^T[s][q] for this wave's 16 q
    f32x4 S[4];
    #pragma unroll
    for (int st=0; st<4; ++st){
      short8 kf0 = *(const short8*)(ks + (st*16+lr)*64 + ((lq  )^(lr&7))*8);
      short8 kf1 = *(const short8*)(ks + (st*16+lr)*64 + ((4+lq)^(lr&7))*8);
      f32x4 z = f32x4{0.f,0.f,0.f,0.f};
      z = __builtin_amdgcn_mfma_f32_16x16x32_bf16(kf0, aq[0], z, 0,0,0);
      z = __builtin_amdgcn_mfma_f32_16x16x32_bf16(kf1, aq[1], z, 0,0,0);
      S[st] = z;
    }
    if (it >= 2*qt){                      // last two tiles overlap the q range
      int qg = q0 + lr;
      #pragma unroll
      for (int st=0;st<4;++st)
        #pragma unroll
        for (int r=0;r<4;++r){
          int sg = s0 + st*16 + lq*4 + r;
          if (sg > qg) S[st][r] = -3e38f;
        }
    }
    // online softmax (q = lr; s-reduction in-lane + 2 shuffles)
    float m = S[0][0];
    #pragma unroll
    for (int st=0;st<4;++st)
      #pragma unroll
      for (int r=0;r<4;++r) m = fmaxf(m, S[st][r]);
    m = fmaxf(m, __shfl_xor(m,16));
    m = fmaxf(m, __shfl_xor(m,32));
    float mnew = fmaxf(mrun, m);
    float alpha = EXP2F(mrun - mnew);
    mrun = mnew;
    float ssum = 0.f;
    #pragma unroll
    for (int st=0;st<4;++st)
      #pragma unroll
      for (int r=0;r<4;++r){ float p = EXP2F(S[st][r]-mnew); S[st][r]=p; ssum+=p; }
    ssum += __shfl_xor(ssum,16);
    ssum += __shfl_xor(ssum,32);
    lrun = lrun*alpha + ssum;
    // P: in-lane pack to K=16 A-fragments
    short4_t pk[4];
    #pragma unroll
    for (int st=0;st<4;++st) pk[st] = pack4(S[st]);
    // rescale O (O rows: q = lq*4+r)
    float af[4];
    #pragma unroll
    for (int r=0;r<4;++r) af[r] = __shfl(alpha, lq*4+r);
    #pragma unroll
    for (int dt=0;dt<4;++dt)
      #pragma unroll
      for (int r=0;r<4;++r) Oacc[dt][r] *= af[r];
    // PV: 16 x mfma_16x16x16
    #pragma unroll
    for (int st=0;st<4;++st){
      #pragma unroll
      for (int dt=0;dt<4;++dt){
        short4_t vf = *(const short4_t*)(vs + (dt*16+lr)*64 + ((2*st+(lq>>1))^(lr&7))*8 + (lq&1)*4);
        Oacc[dt] = MFMA16(pk[st], vf, Oacc[dt]);
      }
    }
  }
  float linv[4];
  #pragma unroll
  for (int r=0;r<4;++r) linv[r] = 1.0f/__shfl(lrun, lq*4+r);
  #pragma unroll
  for (int dt=0;dt<4;++dt)
    #pragma unroll
    for (int r=0;r<4;++r){
      int qg = q0 + lq*4 + r;
      O[(size_t)(bb*T+qg)*E + h*64 + dt*16 + lr] = f2b(Oacc[dt][r]*linv[r]);
    }
}

// ---------------- host ----------------
extern "C" void kernel_launch(void* const* d_in, const int* in_sizes, int n_in,
                              void* d_out, int out_size, void* d_ws, size_t ws_size,
                              hipStream_t stream)
{
  (void)in_sizes; (void)n_in; (void)out_size; (void)ws_size;
  const float* x     = (const float*)d_in[0];
  const float* wq    = (const float*)d_in[1];
  const float* wk    = (const float*)d_in[2];
  const float* wv    = (const float*)d_in[3];
  const float* wproj = (const float*)d_in[4];
  const float* bproj = (const float*)d_in[5];
  const float* g1    = (const float*)d_in[6];
  const float* be1   = (const float*)d_in[7];
  const float* g2    = (const float*)d_in[8];
  const float* be2   = (const float*)d_in[9];
  const float* w1    = (const float*)d_in[10];
  const float* b1    = (const float*)d_in[11];
  const float* w2    = (const float*)d_in[12];
  const float* b2    = (const float*)d_in[13];
  float* out = (float*)d_out;

  char* ws = (char*)d_ws;
  size_t off = 0;
  auto alloc = [&](size_t bytes)->void*{ void* p = ws + off; off += (bytes + 255) & ~(size_t)255; return p; };
  u16* hnorm  = (u16*)alloc((size_t)4096*1024*2);
  u16* qkv    = (u16*)alloc((size_t)4096*3072*2);
  u16* VT     = (u16*)alloc((size_t)32*64*2048*2);
  u16* attnO  = (u16*)alloc((size_t)4096*1024*2);
  u16* x2     = (u16*)alloc((size_t)4096*1024*2);
  u16* h2     = (u16*)alloc((size_t)4096*1024*2);
  u16* ffn1   = (u16*)alloc((size_t)4096*4096*2);
  u16* wqkvT  = (u16*)alloc((size_t)3072*1024*2);
  u16* wprojT = (u16*)alloc((size_t)1024*1024*2);
  u16* w1T    = (u16*)alloc((size_t)4096*1024*2);
  u16* w2T    = (u16*)alloc((size_t)1024*4096*2);

  qkv_repack  <<<dim3(16,48),256,0,stream>>>(wq,wk,wv,wqkvT);
  transpose_bt<<<dim3(16,16),256,0,stream>>>(wproj, wprojT, 1024, 1024);
  transpose_bt<<<dim3(64,16),256,0,stream>>>(w1,    w1T,    4096, 1024);
  transpose_bt<<<dim3(16,64),256,0,stream>>>(w2,    w2T,    1024, 4096);

  ln_kernel<1><<<4096,256,0,stream>>>(x, g1, be1, hnorm);
  gemm256<<<dim3(12,16),512,0,stream>>>(hnorm, wqkvT, qkv, nullptr, 3072, 1024, nullptr, nullptr, 0, 4);
  vtrans<<<dim3(32,32),256,0,stream>>>(qkv, VT);
  attn_kernel<<<dim3(16,32),512,0,stream>>>(qkv, VT, attnO);
  gemm64<<<dim3(16,64),256,0,stream>>>(attnO, wprojT, x2, nullptr, 4096,1024,1024, bproj, hnorm, 0, 4);
  ln_kernel<0><<<4096,256,0,stream>>>(x2, g2, be2, h2);
  gemm256<<<dim3(16,16),512,0,stream>>>(h2, w1T, ffn1, nullptr, 4096, 1024, b1, nullptr, 1, 4);
  gemm64<<<dim3(16,64),256,0,stream>>>(ffn1, w2T, nullptr, out, 4096,1024,4096, b2, h2, 0, 4);
}